// Round 4
// baseline (169.779 us; speedup 1.0000x reference)
//
#include <hip/hip_runtime.h>
#include <hip/hip_bf16.h>
#include <math.h>

typedef __attribute__((ext_vector_type(8))) short short8;
typedef __attribute__((ext_vector_type(4))) float floatx4;

#define MARGIN_C    0.09f
#define ONE_M_EPS   0.99999f
#define NCLS        64
#define ECAP        1024          // per-tile LDS entry cap (expected ~500)

__device__ __forceinline__ unsigned short f2bf(float f) {
    unsigned u = __float_as_uint(f);
    u += 0x7fffu + ((u >> 16) & 1u);
    return (unsigned short)(u >> 16);
}
// order-preserving float<->uint key for atomicMax on floats
__device__ __forceinline__ unsigned fkey(float f) {
    unsigned u = __float_as_uint(f);
    return (u >> 31) ? ~u : (u | 0x80000000u);
}
__device__ __forceinline__ float fdec(unsigned k) {
    return __uint_as_float((k >> 31) ? (k & 0x7fffffffu) : ~k);
}

__device__ __forceinline__ void gld16(const void* g, void* l) {
    __builtin_amdgcn_global_load_lds(
        (const __attribute__((address_space(1))) void*)g,
        (__attribute__((address_space(3))) void*)l, 16, 0, 0);
}

// ---------- fp32 -> bf16 cvt; zero stats (negsum/negmaxkey/possum/nposf/ctr) --
__global__ __launch_bounds__(256) void cvt_bf16(const float* __restrict__ in,
                                                unsigned short* __restrict__ out,
                                                float* __restrict__ statz,
                                                int n4, int nz4) {
    int i = blockIdx.x * 256 + threadIdx.x;
    if (i < nz4) ((float4*)statz)[i] = make_float4(0.f, 0.f, 0.f, 0.f);
    if (i >= n4) return;
    float4 v = ((const float4*)in)[i];
    ushort4 o;
    o.x = f2bf(v.x); o.y = f2bf(v.y); o.z = f2bf(v.z); o.w = f2bf(v.w);
    ((ushort4*)out)[i] = o;
}

// ---------- GEMM (lower-tri tiles) + fused neg stats + positive-pair record --
// 128x128 tile, BK=32, single-buffer global_load_lds staging (m97 structure).
__global__ __launch_bounds__(256) void gemm_fused(const unsigned short* __restrict__ fb,
                                                  const int* __restrict__ labels,
                                                  float* __restrict__ negsum,
                                                  unsigned* __restrict__ negmax,
                                                  uint2* __restrict__ pairs,
                                                  unsigned* __restrict__ ctr,
                                                  int Bn, int Dn) {
    __shared__ __align__(16) unsigned short As[4096];   // 8KB, reused as ebuf post-loop
    __shared__ __align__(16) unsigned short Bs[4096];   // 8KB
    __shared__ int Lrow[128], Lcol[128];
    __shared__ unsigned lcnt, gbase;
    uint2* ebuf = (uint2*)As;                           // 1024 entries

    const int bid = blockIdx.x;
    int by = (int)((sqrtf(8.f * (float)bid + 1.f) - 1.f) * 0.5f);
    while ((by + 1) * (by + 2) / 2 <= bid) by++;
    while (by * (by + 1) / 2 > bid) by--;
    const int bx = bid - by * (by + 1) / 2;

    const int t = threadIdx.x;
    const int wave = t >> 6, lane = t & 63;
    const int wr = wave >> 1, wc = wave & 1;
    const int quad = lane >> 4, m16 = lane & 15;

    if (t < 128) Lrow[t] = labels[by * 128 + t];
    else         Lcol[t - 128] = labels[bx * 128 + (t - 128)];
    if (t == 0) lcnt = 0;

    // staging: thread t -> LDS offset t*16B (rows lr, lr+64), k-chunk rotated
    const int lr = t >> 2, slot = t & 3, kf = (slot + lr) & 3;
    const unsigned short* gA0 = fb + (size_t)(by * 128 + lr) * Dn + kf * 8;
    const unsigned short* gB0 = fb + (size_t)(bx * 128 + lr) * Dn + kf * 8;
    const unsigned short* gA1 = gA0 + (size_t)64 * Dn;
    const unsigned short* gB1 = gB0 + (size_t)64 * Dn;
    unsigned short* lA0 = As + t * 8;
    unsigned short* lA1 = As + 2048 + t * 8;
    unsigned short* lB0 = Bs + t * 8;
    unsigned short* lB1 = Bs + 2048 + t * 8;

    floatx4 acc[4][4];
#pragma unroll
    for (int i = 0; i < 4; i++)
#pragma unroll
        for (int j = 0; j < 4; j++) acc[i][j] = (floatx4){0.f, 0.f, 0.f, 0.f};

    const unsigned short* pa = As + (wr * 64 + m16) * 32 + ((quad - m16) & 3) * 8;
    const unsigned short* pb = Bs + (wc * 64 + m16) * 32 + ((quad - m16) & 3) * 8;

    for (int k0 = 0; k0 < Dn; k0 += 32) {
        gld16(gA0 + k0, lA0);
        gld16(gA1 + k0, lA1);
        gld16(gB0 + k0, lB0);
        gld16(gB1 + k0, lB1);
        __syncthreads();
        short8 af[4], bfr[4];
#pragma unroll
        for (int i = 0; i < 4; i++) af[i]  = *(const short8*)(pa + i * 512);
#pragma unroll
        for (int i = 0; i < 4; i++) bfr[i] = *(const short8*)(pb + i * 512);
#pragma unroll
        for (int i = 0; i < 4; i++)
#pragma unroll
            for (int j = 0; j < 4; j++)
                acc[i][j] = __builtin_amdgcn_mfma_f32_16x16x32_bf16(af[i], bfr[j], acc[i][j], 0, 0, 0);
        __syncthreads();   // all reads of As/Bs done before next stage overwrites
    }
    // After the final barrier As is dead -> safe to reuse as ebuf.

    // ----- epilogue: C/D layout col = m16 (+j*16), row = quad*4 + r (+i*16) --
    int cl[4];
#pragma unroll
    for (int j = 0; j < 4; j++) cl[j] = Lcol[wc * 64 + j * 16 + m16];
    const bool offd = (bx != by);

    float nsm[4] = {0.f, 0.f, 0.f, 0.f};
    float nmm[4] = {-INFINITY, -INFINITY, -INFINITY, -INFINITY};

#pragma unroll
    for (int i = 0; i < 4; i++) {
#pragma unroll
        for (int r = 0; r < 4; r++) {
            const int rowl = wr * 64 + i * 16 + quad * 4 + r;
            const int rl = Lrow[rowl];
            const int gr = by * 128 + rowl;
            float ns = 0.f, nm = -INFINITY;
#pragma unroll
            for (int j = 0; j < 4; j++) {
                float s = acc[i][j][r];
                if (cl[j] != rl) {
                    float e = __expf(40.f * s);
                    ns += e;
                    nm = fmaxf(nm, s);
                    nsm[j] += e;
                    nmm[j] = fmaxf(nmm[j], s);
                } else if (s < ONE_M_EPS) {
                    // positive candidate (mask vs negmax applied later)
                    const int gc = bx * 128 + wc * 64 + j * 16 + m16;
                    unsigned sl = atomicAdd(&lcnt, 1);
                    if (sl < ECAP) ebuf[sl] = make_uint2((unsigned)gr, __float_as_uint(s));
                    else { unsigned g = atomicAdd(ctr, 1); pairs[g] = make_uint2((unsigned)gr, __float_as_uint(s)); }
                    if (offd) {
                        sl = atomicAdd(&lcnt, 1);
                        if (sl < ECAP) ebuf[sl] = make_uint2((unsigned)gc, __float_as_uint(s));
                        else { unsigned g = atomicAdd(ctr, 1); pairs[g] = make_uint2((unsigned)gc, __float_as_uint(s)); }
                    }
                }
            }
#pragma unroll
            for (int o = 8; o; o >>= 1) {
                ns += __shfl_down(ns, o, 64);
                nm = fmaxf(nm, __shfl_down(nm, o, 64));
            }
            if (m16 == 0) {
                atomicAdd(negsum + gr, ns);
                atomicMax(negmax + gr, fkey(nm));
            }
        }
    }
    if (offd) {   // mirror negative stats: this tile's cols are rows bx*128..
#pragma unroll
        for (int j = 0; j < 4; j++) {
            float v = nsm[j], m = nmm[j];
            v += __shfl_down(v, 16, 64);
            m = fmaxf(m, __shfl_down(m, 16, 64));
            v += __shfl_down(v, 32, 64);
            m = fmaxf(m, __shfl_down(m, 32, 64));
            if (quad == 0) {
                const int gc = bx * 128 + wc * 64 + j * 16 + m16;
                atomicAdd(negsum + gc, v);
                atomicMax(negmax + gc, fkey(m));
            }
        }
    }

    // flush LDS-staged positive entries (one global atomic per block)
    __syncthreads();
    if (t == 0) {
        unsigned n = (lcnt < ECAP) ? lcnt : ECAP;
        gbase = atomicAdd(ctr, n);
    }
    __syncthreads();
    const unsigned n = (lcnt < ECAP) ? lcnt : ECAP;
    for (unsigned e = t; e < n; e += 256) pairs[gbase + e] = ebuf[e];
}

// ---------- apply negmax-dependent mask to recorded positive pairs ----------
__global__ __launch_bounds__(256) void pos_apply(const uint2* __restrict__ pairs,
                                                 const unsigned* __restrict__ ctr,
                                                 const unsigned* __restrict__ negmax,
                                                 float* __restrict__ possum,
                                                 float* __restrict__ nposf) {
    const unsigned n = *ctr;
    for (unsigned i = blockIdx.x * 256 + threadIdx.x; i < n; i += gridDim.x * 256) {
        uint2 e = pairs[i];
        const float s = __uint_as_float(e.y);
        const float mx = fdec(negmax[e.x]);
        if ((s - MARGIN_C) < mx) {
            atomicAdd(possum + e.x, __expf(-2.f * s));
            atomicAdd(nposf + e.x, 1.f);
        }
    }
}

// ---------- finalize: class histogram + per-row loss + mean (single block) ---
__global__ __launch_bounds__(1024) void finalize(const float* __restrict__ negsum,
                                                 const float* __restrict__ possum,
                                                 const float* __restrict__ nposf,
                                                 const int* __restrict__ labels,
                                                 float* __restrict__ out, int Bn) {
    __shared__ int hist[NCLS];
    __shared__ float red[16];
    const int t = threadIdx.x;
    const int wave = t >> 6, lane = t & 63;
    if (t < NCLS) hist[t] = 0;
    __syncthreads();
    for (int i = t; i < Bn; i += 1024) atomicAdd(&hist[labels[i]], 1);
    __syncthreads();
    float acc = 0.f;
    for (int i = t; i < Bn; i += 1024) {
        const int nneg = Bn - hist[labels[i]];
        const float np = nposf[i];
        if (nneg >= 1 && np >= 0.5f) {
            float pl = 0.5f * logf((possum[i] + expf(-2.f * 0.501f)) / (np + 1.f));
            float nl = (1.f / 40.f) * logf((negsum[i] + expf(40.f * 0.531f)) / ((float)nneg + 1.f));
            acc += logf(5.33f + expf(pl + nl));
        }
    }
#pragma unroll
    for (int o = 32; o; o >>= 1) acc += __shfl_down(acc, o, 64);
    if (lane == 0) red[wave] = acc;
    __syncthreads();
    if (t == 0) {
        float s = 0.f;
        for (int w = 0; w < 16; w++) s += red[w];
        out[0] = s / (float)Bn;
    }
}

extern "C" void kernel_launch(void* const* d_in, const int* in_sizes, int n_in,
                              void* d_out, int out_size, void* d_ws, size_t ws_size,
                              hipStream_t stream) {
    const float* feats = (const float*)d_in[0];
    const int* labels  = (const int*)d_in[1];
    float* out = (float*)d_out;

    const int Bn = in_sizes[1];           // 4096
    const int Dn = in_sizes[0] / Bn;      // 1024

    unsigned short* fb = (unsigned short*)d_ws;                 // bf16 feats [Bn][Dn]
    float* stats   = (float*)(fb + (size_t)Bn * Dn);
    float* negsum  = stats;                                     // [Bn]
    unsigned* negmax = (unsigned*)(stats + Bn);                 // [Bn] keyed
    float* possum  = stats + 2 * Bn;                            // [Bn]
    float* nposf   = stats + 3 * Bn;                            // [Bn]
    unsigned* ctr  = (unsigned*)(stats + 4 * Bn);               // [1] (+pad to 16)
    uint2* pairs   = (uint2*)(stats + 4 * Bn + 16);             // ~1M entries fits ws

    const int n4  = (Bn * Dn) / 4;
    const int nz4 = (4 * Bn + 16) / 4;
    cvt_bf16<<<(n4 + 255) / 256, 256, 0, stream>>>(feats, fb, stats, n4, nz4);

    const int nt = Bn / 128;
    const int ntri = nt * (nt + 1) / 2;   // 528
    gemm_fused<<<ntri, 256, 0, stream>>>(fb, labels, negsum, negmax, pairs, ctr, Bn, Dn);

    pos_apply<<<256, 256, 0, stream>>>(pairs, ctr, negmax, possum, nposf);

    finalize<<<1, 1024, 0, stream>>>(negsum, possum, nposf, labels, out, Bn);
}

// Round 5
// 156.667 us; speedup vs baseline: 1.0837x; 1.0837x over previous
//
#include <hip/hip_runtime.h>
#include <hip/hip_bf16.h>
#include <math.h>

typedef __attribute__((ext_vector_type(8))) short short8;
typedef __attribute__((ext_vector_type(4))) float floatx4;

#define MARGIN_C    0.09f
#define ONE_M_EPS   0.99999f
#define NCLS        64
#define ECAP        2048          // ebuf entries (16KB LDS reuse); expected ~500/tile

__device__ __forceinline__ unsigned short f2bf(float f) {
    unsigned u = __float_as_uint(f);
    u += 0x7fffu + ((u >> 16) & 1u);
    return (unsigned short)(u >> 16);
}
// order-preserving float<->uint key for atomicMax on floats
__device__ __forceinline__ unsigned fkey(float f) {
    unsigned u = __float_as_uint(f);
    return (u >> 31) ? ~u : (u | 0x80000000u);
}
__device__ __forceinline__ float fdec(unsigned k) {
    return __uint_as_float((k >> 31) ? (k & 0x7fffffffu) : ~k);
}

// ---------- fp32 -> bf16 cvt; zero stats ------------------------------------
__global__ __launch_bounds__(256) void cvt_bf16(const float* __restrict__ in,
                                                unsigned short* __restrict__ out,
                                                float* __restrict__ statz,
                                                int n4, int nz4) {
    int i = blockIdx.x * 256 + threadIdx.x;
    if (i < nz4) ((float4*)statz)[i] = make_float4(0.f, 0.f, 0.f, 0.f);
    if (i >= n4) return;
    float4 v = ((const float4*)in)[i];
    ushort4 o;
    o.x = f2bf(v.x); o.y = f2bf(v.y); o.z = f2bf(v.z); o.w = f2bf(v.w);
    ((ushort4*)out)[i] = o;
}

// ---------- GEMM (lower-tri tiles) + fused neg stats + positive-pair record --
// 128x128 tile, BK=32, reg-prefetch double-buffered LDS (round-3 K-loop).
// Recording uses wave-scan slot allocation: 4 LDS atomics/block, not ~500.
__global__ __launch_bounds__(256) void gemm_fused(const unsigned short* __restrict__ fb,
                                                  const int* __restrict__ labels,
                                                  float* __restrict__ negsum,
                                                  unsigned* __restrict__ negmax,
                                                  uint2* __restrict__ pairs,
                                                  unsigned* __restrict__ ctr,
                                                  int Bn, int Dn) {
    __shared__ __align__(16) unsigned short As[2][4096];   // 16KB; dead after loop -> ebuf
    __shared__ __align__(16) unsigned short Bs[2][4096];
    __shared__ int Lrow[128], Lcol[128];
    __shared__ unsigned lcnt, gbase;
    uint2* ebuf = (uint2*)As;                              // 2048 entries

    const int bid = blockIdx.x;
    int by = (int)((sqrtf(8.f * (float)bid + 1.f) - 1.f) * 0.5f);
    while ((by + 1) * (by + 2) / 2 <= bid) by++;
    while (by * (by + 1) / 2 > bid) by--;
    const int bx = bid - by * (by + 1) / 2;

    const int t = threadIdx.x;
    const int wave = t >> 6, lane = t & 63;
    const int wr = wave >> 1, wc = wave & 1;
    const int quad = lane >> 4, m16 = lane & 15;

    if (t < 128) Lrow[t] = labels[by * 128 + t];
    else         Lcol[t - 128] = labels[bx * 128 + (t - 128)];
    if (t == 0) lcnt = 0;

    const int lr = t >> 2, slot = t & 3, kf = (slot + lr) & 3;
    const unsigned short* gA0 = fb + (size_t)(by * 128 + lr) * Dn + kf * 8;
    const unsigned short* gB0 = fb + (size_t)(bx * 128 + lr) * Dn + kf * 8;
    const unsigned short* gA1 = gA0 + (size_t)64 * Dn;
    const unsigned short* gB1 = gB0 + (size_t)64 * Dn;

    floatx4 acc[4][4];
#pragma unroll
    for (int i = 0; i < 4; i++)
#pragma unroll
        for (int j = 0; j < 4; j++) acc[i][j] = (floatx4){0.f, 0.f, 0.f, 0.f};

    const int fragA = (wr * 64 + m16) * 32 + ((quad - m16) & 3) * 8;
    const int fragB = (wc * 64 + m16) * 32 + ((quad - m16) & 3) * 8;

    const int NS = Dn / 32;
    uint4 ra0 = *(const uint4*)gA0, ra1 = *(const uint4*)gA1;
    uint4 rb0 = *(const uint4*)gB0, rb1 = *(const uint4*)gB1;
    *(uint4*)(&As[0][t * 8]) = ra0;  *(uint4*)(&As[0][2048 + t * 8]) = ra1;
    *(uint4*)(&Bs[0][t * 8]) = rb0;  *(uint4*)(&Bs[0][2048 + t * 8]) = rb1;
    ra0 = *(const uint4*)(gA0 + 32); ra1 = *(const uint4*)(gA1 + 32);
    rb0 = *(const uint4*)(gB0 + 32); rb1 = *(const uint4*)(gB1 + 32);
    __syncthreads();

    for (int s = 0; s < NS; s++) {
        const unsigned short* as_ = As[s & 1];
        const unsigned short* bs_ = Bs[s & 1];
        short8 af[4], bfr[4];
#pragma unroll
        for (int i = 0; i < 4; i++) af[i]  = *(const short8*)(as_ + fragA + i * 512);
#pragma unroll
        for (int i = 0; i < 4; i++) bfr[i] = *(const short8*)(bs_ + fragB + i * 512);
#pragma unroll
        for (int i = 0; i < 4; i++)
#pragma unroll
            for (int j = 0; j < 4; j++)
                acc[i][j] = __builtin_amdgcn_mfma_f32_16x16x32_bf16(af[i], bfr[j], acc[i][j], 0, 0, 0);
        if (s + 1 < NS) {
            __syncthreads();
            unsigned short* aw = As[(s + 1) & 1];
            unsigned short* bw = Bs[(s + 1) & 1];
            *(uint4*)(&aw[t * 8]) = ra0;  *(uint4*)(&aw[2048 + t * 8]) = ra1;
            *(uint4*)(&bw[t * 8]) = rb0;  *(uint4*)(&bw[2048 + t * 8]) = rb1;
            if (s + 2 < NS) {
                const int ko = (s + 2) * 32;
                ra0 = *(const uint4*)(gA0 + ko); ra1 = *(const uint4*)(gA1 + ko);
                rb0 = *(const uint4*)(gB0 + ko); rb1 = *(const uint4*)(gB1 + ko);
            }
            __syncthreads();
        }
    }
    __syncthreads();   // all LDS reads done: As reusable as ebuf

    // ----- epilogue 1: negative stats (C/D: col = m16+j*16, row = quad*4+r+i*16)
    int cl[4];
#pragma unroll
    for (int j = 0; j < 4; j++) cl[j] = Lcol[wc * 64 + j * 16 + m16];
    const bool offd = (bx != by);

    float nsm[4] = {0.f, 0.f, 0.f, 0.f};
    float nmm[4] = {-INFINITY, -INFINITY, -INFINITY, -INFINITY};

#pragma unroll
    for (int i = 0; i < 4; i++) {
#pragma unroll
        for (int r = 0; r < 4; r++) {
            const int rowl = wr * 64 + i * 16 + quad * 4 + r;
            const int rl = Lrow[rowl];
            const int gr = by * 128 + rowl;
            float ns = 0.f, nm = -INFINITY;
#pragma unroll
            for (int j = 0; j < 4; j++) {
                float s = acc[i][j][r];
                if (cl[j] != rl) {
                    float e = __expf(40.f * s);
                    ns += e;
                    nm = fmaxf(nm, s);
                    nsm[j] += e;
                    nmm[j] = fmaxf(nmm[j], s);
                }
            }
#pragma unroll
            for (int o = 8; o; o >>= 1) {
                ns += __shfl_down(ns, o, 64);
                nm = fmaxf(nm, __shfl_down(nm, o, 64));
            }
            if (m16 == 0) {
                atomicAdd(negsum + gr, ns);
                atomicMax(negmax + gr, fkey(nm));
            }
        }
    }
    if (offd) {
#pragma unroll
        for (int j = 0; j < 4; j++) {
            float v = nsm[j], m = nmm[j];
            v += __shfl_down(v, 16, 64);
            m = fmaxf(m, __shfl_down(m, 16, 64));
            v += __shfl_down(v, 32, 64);
            m = fmaxf(m, __shfl_down(m, 32, 64));
            if (quad == 0) {
                const int gc = bx * 128 + wc * 64 + j * 16 + m16;
                atomicAdd(negsum + gc, v);
                atomicMax(negmax + gc, fkey(m));
            }
        }
    }

    // ----- epilogue 2: positive-pair recording, scan-based slot allocation ---
    const unsigned inc = offd ? 2u : 1u;
    // phase A: branchless count
    unsigned cnt = 0;
#pragma unroll
    for (int i = 0; i < 4; i++)
#pragma unroll
        for (int r = 0; r < 4; r++) {
            const int rl = Lrow[wr * 64 + i * 16 + quad * 4 + r];
#pragma unroll
            for (int j = 0; j < 4; j++) {
                const bool pos = (cl[j] == rl) & (acc[i][j][r] < ONE_M_EPS);
                cnt += pos ? inc : 0u;
            }
        }
    // wave inclusive scan (6 steps)
    unsigned scan = cnt;
#pragma unroll
    for (int o = 1; o < 64; o <<= 1) {
        unsigned v = __shfl_up(scan, o, 64);
        if (lane >= o) scan += v;
    }
    const unsigned excl = scan - cnt;
    unsigned base0 = 0;
    if (lane == 63) base0 = atomicAdd(&lcnt, scan);   // one atomic per wave
    base0 = __shfl(base0, 63, 64);
    unsigned slot2 = base0 + excl;
    // phase B: write entries
    if (cnt) {
#pragma unroll
        for (int i = 0; i < 4; i++)
#pragma unroll
            for (int r = 0; r < 4; r++) {
                const int rowl = wr * 64 + i * 16 + quad * 4 + r;
                const int rl = Lrow[rowl];
                const int gr = by * 128 + rowl;
#pragma unroll
                for (int j = 0; j < 4; j++) {
                    const float s = acc[i][j][r];
                    if ((cl[j] == rl) & (s < ONE_M_EPS)) {
                        const int gc = bx * 128 + wc * 64 + j * 16 + m16;
                        uint2 e1 = make_uint2((unsigned)gr, __float_as_uint(s));
                        if (slot2 < ECAP) ebuf[slot2] = e1;
                        else { unsigned g = atomicAdd(ctr, 1); pairs[g] = e1; }
                        slot2++;
                        if (offd) {
                            uint2 e2 = make_uint2((unsigned)gc, __float_as_uint(s));
                            if (slot2 < ECAP) ebuf[slot2] = e2;
                            else { unsigned g = atomicAdd(ctr, 1); pairs[g] = e2; }
                            slot2++;
                        }
                    }
                }
            }
    }

    // flush ebuf (one global atomic per block)
    __syncthreads();
    if (t == 0) {
        unsigned n = (lcnt < ECAP) ? lcnt : ECAP;
        gbase = atomicAdd(ctr, n);
    }
    __syncthreads();
    const unsigned n = (lcnt < ECAP) ? lcnt : ECAP;
    for (unsigned e = t; e < n; e += 256) pairs[gbase + e] = ebuf[e];
}

// ---------- apply negmax-dependent mask to recorded positive pairs ----------
__global__ __launch_bounds__(256) void pos_apply(const uint2* __restrict__ pairs,
                                                 const unsigned* __restrict__ ctr,
                                                 const unsigned* __restrict__ negmax,
                                                 float* __restrict__ possum,
                                                 float* __restrict__ nposf) {
    const unsigned n = *ctr;
    for (unsigned i = blockIdx.x * 256 + threadIdx.x; i < n; i += gridDim.x * 256) {
        uint2 e = pairs[i];
        const float s = __uint_as_float(e.y);
        const float mx = fdec(negmax[e.x]);
        if ((s - MARGIN_C) < mx) {
            atomicAdd(possum + e.x, __expf(-2.f * s));
            atomicAdd(nposf + e.x, 1.f);
        }
    }
}

// ---------- finalize: class histogram + per-row loss + mean (single block) ---
__global__ __launch_bounds__(1024) void finalize(const float* __restrict__ negsum,
                                                 const float* __restrict__ possum,
                                                 const float* __restrict__ nposf,
                                                 const int* __restrict__ labels,
                                                 float* __restrict__ out, int Bn) {
    __shared__ int hist[NCLS];
    __shared__ float red[16];
    const int t = threadIdx.x;
    const int wave = t >> 6, lane = t & 63;
    if (t < NCLS) hist[t] = 0;
    __syncthreads();
    for (int i = t; i < Bn; i += 1024) atomicAdd(&hist[labels[i]], 1);
    __syncthreads();
    float acc = 0.f;
    for (int i = t; i < Bn; i += 1024) {
        const int nneg = Bn - hist[labels[i]];
        const float np = nposf[i];
        if (nneg >= 1 && np >= 0.5f) {
            float pl = 0.5f * logf((possum[i] + expf(-2.f * 0.501f)) / (np + 1.f));
            float nl = (1.f / 40.f) * logf((negsum[i] + expf(40.f * 0.531f)) / ((float)nneg + 1.f));
            acc += logf(5.33f + expf(pl + nl));
        }
    }
#pragma unroll
    for (int o = 32; o; o >>= 1) acc += __shfl_down(acc, o, 64);
    if (lane == 0) red[wave] = acc;
    __syncthreads();
    if (t == 0) {
        float s = 0.f;
        for (int w = 0; w < 16; w++) s += red[w];
        out[0] = s / (float)Bn;
    }
}

extern "C" void kernel_launch(void* const* d_in, const int* in_sizes, int n_in,
                              void* d_out, int out_size, void* d_ws, size_t ws_size,
                              hipStream_t stream) {
    const float* feats = (const float*)d_in[0];
    const int* labels  = (const int*)d_in[1];
    float* out = (float*)d_out;

    const int Bn = in_sizes[1];           // 4096
    const int Dn = in_sizes[0] / Bn;      // 1024

    unsigned short* fb = (unsigned short*)d_ws;                 // bf16 feats [Bn][Dn]
    float* stats   = (float*)(fb + (size_t)Bn * Dn);
    float* negsum  = stats;                                     // [Bn]
    unsigned* negmax = (unsigned*)(stats + Bn);                 // [Bn] keyed
    float* possum  = stats + 2 * Bn;                            // [Bn]
    float* nposf   = stats + 3 * Bn;                            // [Bn]
    unsigned* ctr  = (unsigned*)(stats + 4 * Bn);               // [1] (+pad 16)
    uint2* pairs   = (uint2*)(stats + 4 * Bn + 16);

    const int n4  = (Bn * Dn) / 4;
    const int nz4 = (4 * Bn + 16) / 4;
    cvt_bf16<<<(n4 + 255) / 256, 256, 0, stream>>>(feats, fb, stats, n4, nz4);

    const int nt = Bn / 128;
    const int ntri = nt * (nt + 1) / 2;   // 528
    gemm_fused<<<ntri, 256, 0, stream>>>(fb, labels, negsum, negmax, pairs, ctr, Bn, Dn);

    pos_apply<<<256, 256, 0, stream>>>(pairs, ctr, negmax, possum, nposf);

    finalize<<<1, 1024, 0, stream>>>(negsum, possum, nposf, labels, out, Bn);
}

// Round 6
// 124.976 us; speedup vs baseline: 1.3585x; 1.2536x over previous
//
#include <hip/hip_runtime.h>
#include <hip/hip_bf16.h>
#include <math.h>

typedef __attribute__((ext_vector_type(8))) short short8;
typedef __attribute__((ext_vector_type(4))) float floatx4;

#define MARGIN_C    0.09f
#define ONE_M_EPS   0.99999f
#define NCLS        64
#define MEMSTRIDE   256

__device__ __forceinline__ unsigned short f2bf(float f) {
    unsigned u = __float_as_uint(f);
    u += 0x7fffu + ((u >> 16) & 1u);
    return (unsigned short)(u >> 16);
}
__device__ __forceinline__ float bf2f(unsigned short v) {
    return __uint_as_float(((unsigned)v) << 16);
}
// order-preserving float<->uint key for atomicMax on floats
__device__ __forceinline__ unsigned fkey(float f) {
    unsigned u = __float_as_uint(f);
    return (u >> 31) ? ~u : (u | 0x80000000u);
}
__device__ __forceinline__ float fdec(unsigned k) {
    return __uint_as_float((k >> 31) ? (k & 0x7fffffffu) : ~k);
}

// ---------- fused: fp32->bf16 cvt + stat zeroing + per-class member lists ----
// blocks [0, ncvt): conversion; blocks [ncvt, ncvt+NCLS): build members.
__global__ __launch_bounds__(256) void cvt_build(const float* __restrict__ in,
                                                 unsigned short* __restrict__ out,
                                                 float* __restrict__ statz,   // negsum+negmax: 2*Bn floats
                                                 const int* __restrict__ labels,
                                                 int* __restrict__ members,
                                                 int* __restrict__ classCount,
                                                 int n4, int nz4, int ncvt, int Bn) {
    __shared__ int cnt;
    const int bid = blockIdx.x;
    const int t = threadIdx.x;
    if (bid < ncvt) {
        int i = bid * 256 + t;
        if (i < nz4) ((float4*)statz)[i] = make_float4(0.f, 0.f, 0.f, 0.f);
        if (i >= n4) return;
        float4 v = ((const float4*)in)[i];
        ushort4 o;
        o.x = f2bf(v.x); o.y = f2bf(v.y); o.z = f2bf(v.z); o.w = f2bf(v.w);
        ((ushort4*)out)[i] = o;
    } else {
        const int c = bid - ncvt;
        if (t == 0) cnt = 0;
        __syncthreads();
        for (int j = t; j < Bn; j += 256) {
            if (labels[j] == c) {
                int p = atomicAdd(&cnt, 1);
                if (p < MEMSTRIDE) members[c * MEMSTRIDE + p] = j;
            }
        }
        __syncthreads();
        if (t == 0) classCount[c] = (cnt < MEMSTRIDE) ? cnt : MEMSTRIDE;
    }
}

// ---------- GEMM (lower-tri tiles) + fused neg stats + pos scatter ----------
// 128x128 tile, BK=32, reg-prefetch double-buffered LDS (round-3 K-loop).
// Single-pass epilogue: negative stats via quad-reduce + atomics; positive
// candidates scattered as bf16 into pairsim[r*Bn+c] (rare predicated stores).
__global__ __launch_bounds__(256) void gemm_fused(const unsigned short* __restrict__ fb,
                                                  const int* __restrict__ labels,
                                                  float* __restrict__ negsum,
                                                  unsigned* __restrict__ negmax,
                                                  unsigned short* __restrict__ pairsim,
                                                  int Bn, int Dn) {
    __shared__ __align__(16) unsigned short As[2][4096];
    __shared__ __align__(16) unsigned short Bs[2][4096];
    __shared__ int Lrow[128], Lcol[128];

    const int bid = blockIdx.x;
    int by = (int)((sqrtf(8.f * (float)bid + 1.f) - 1.f) * 0.5f);
    while ((by + 1) * (by + 2) / 2 <= bid) by++;
    while (by * (by + 1) / 2 > bid) by--;
    const int bx = bid - by * (by + 1) / 2;

    const int t = threadIdx.x;
    const int wave = t >> 6, lane = t & 63;
    const int wr = wave >> 1, wc = wave & 1;
    const int quad = lane >> 4, m16 = lane & 15;

    if (t < 128) Lrow[t] = labels[by * 128 + t];
    else         Lcol[t - 128] = labels[bx * 128 + (t - 128)];

    const int lr = t >> 2, slot = t & 3, kf = (slot + lr) & 3;
    const unsigned short* gA0 = fb + (size_t)(by * 128 + lr) * Dn + kf * 8;
    const unsigned short* gB0 = fb + (size_t)(bx * 128 + lr) * Dn + kf * 8;
    const unsigned short* gA1 = gA0 + (size_t)64 * Dn;
    const unsigned short* gB1 = gB0 + (size_t)64 * Dn;

    floatx4 acc[4][4];
#pragma unroll
    for (int i = 0; i < 4; i++)
#pragma unroll
        for (int j = 0; j < 4; j++) acc[i][j] = (floatx4){0.f, 0.f, 0.f, 0.f};

    const int fragA = (wr * 64 + m16) * 32 + ((quad - m16) & 3) * 8;
    const int fragB = (wc * 64 + m16) * 32 + ((quad - m16) & 3) * 8;

    const int NS = Dn / 32;
    uint4 ra0 = *(const uint4*)gA0, ra1 = *(const uint4*)gA1;
    uint4 rb0 = *(const uint4*)gB0, rb1 = *(const uint4*)gB1;
    *(uint4*)(&As[0][t * 8]) = ra0;  *(uint4*)(&As[0][2048 + t * 8]) = ra1;
    *(uint4*)(&Bs[0][t * 8]) = rb0;  *(uint4*)(&Bs[0][2048 + t * 8]) = rb1;
    ra0 = *(const uint4*)(gA0 + 32); ra1 = *(const uint4*)(gA1 + 32);
    rb0 = *(const uint4*)(gB0 + 32); rb1 = *(const uint4*)(gB1 + 32);
    __syncthreads();

    for (int s = 0; s < NS; s++) {
        const unsigned short* as_ = As[s & 1];
        const unsigned short* bs_ = Bs[s & 1];
        short8 af[4], bfr[4];
#pragma unroll
        for (int i = 0; i < 4; i++) af[i]  = *(const short8*)(as_ + fragA + i * 512);
#pragma unroll
        for (int i = 0; i < 4; i++) bfr[i] = *(const short8*)(bs_ + fragB + i * 512);
#pragma unroll
        for (int i = 0; i < 4; i++)
#pragma unroll
            for (int j = 0; j < 4; j++)
                acc[i][j] = __builtin_amdgcn_mfma_f32_16x16x32_bf16(af[i], bfr[j], acc[i][j], 0, 0, 0);
        if (s + 1 < NS) {
            __syncthreads();
            unsigned short* aw = As[(s + 1) & 1];
            unsigned short* bw = Bs[(s + 1) & 1];
            *(uint4*)(&aw[t * 8]) = ra0;  *(uint4*)(&aw[2048 + t * 8]) = ra1;
            *(uint4*)(&bw[t * 8]) = rb0;  *(uint4*)(&bw[2048 + t * 8]) = rb1;
            if (s + 2 < NS) {
                const int ko = (s + 2) * 32;
                ra0 = *(const uint4*)(gA0 + ko); ra1 = *(const uint4*)(gA1 + ko);
                rb0 = *(const uint4*)(gB0 + ko); rb1 = *(const uint4*)(gB1 + ko);
            }
            __syncthreads();
        }
    }

    // ----- single-pass epilogue (C/D: col = m16 + j*16, row = quad*4+r + i*16)
    const bool offd = (bx != by);
    int cl[4], gc[4];
#pragma unroll
    for (int j = 0; j < 4; j++) {
        cl[j] = Lcol[wc * 64 + j * 16 + m16];
        gc[j] = bx * 128 + wc * 64 + j * 16 + m16;
    }

    float nsm[4] = {0.f, 0.f, 0.f, 0.f};
    float nmm[4] = {-INFINITY, -INFINITY, -INFINITY, -INFINITY};

#pragma unroll
    for (int i = 0; i < 4; i++) {
#pragma unroll
        for (int r = 0; r < 4; r++) {
            const int rowl = wr * 64 + i * 16 + quad * 4 + r;
            const int rl = Lrow[rowl];
            const int gr = by * 128 + rowl;
            float ns = 0.f, nm = -INFINITY;
#pragma unroll
            for (int j = 0; j < 4; j++) {
                const float s = acc[i][j][r];
                if (cl[j] != rl) {
                    const float e = __expf(40.f * s);
                    ns += e;
                    nm = fmaxf(nm, s);
                    nsm[j] += e;
                    nmm[j] = fmaxf(nmm[j], s);
                } else if ((gr != gc[j]) & (s < ONE_M_EPS)) {
                    const unsigned short v = f2bf(s);
                    pairsim[(size_t)gr * Bn + gc[j]] = v;
                    if (offd) pairsim[(size_t)gc[j] * Bn + gr] = v;
                }
            }
#pragma unroll
            for (int o = 8; o; o >>= 1) {
                ns += __shfl_down(ns, o, 64);
                nm = fmaxf(nm, __shfl_down(nm, o, 64));
            }
            if (m16 == 0) {
                atomicAdd(negsum + gr, ns);
                atomicMax(negmax + gr, fkey(nm));
            }
        }
    }
    if (offd) {   // mirror negative stats: this tile's cols are rows bx*128..
#pragma unroll
        for (int j = 0; j < 4; j++) {
            float v = nsm[j], m = nmm[j];
            v += __shfl_down(v, 16, 64);
            m = fmaxf(m, __shfl_down(m, 16, 64));
            v += __shfl_down(v, 32, 64);
            m = fmaxf(m, __shfl_down(m, 32, 64));
            if (quad == 0) {
                atomicAdd(negsum + gc[j], v);
                atomicMax(negmax + gc[j], fkey(m));
            }
        }
    }
}

// ---------- positives: one wave per row, gather class members' pairsim ------
__global__ __launch_bounds__(256) void pos_apply(const unsigned short* __restrict__ pairsim,
                                                 const int* __restrict__ labels,
                                                 const int* __restrict__ members,
                                                 const int* __restrict__ classCount,
                                                 const unsigned* __restrict__ negmax,
                                                 float* __restrict__ possum,
                                                 float* __restrict__ nposf, int Bn) {
    const int t = threadIdx.x;
    const int wave = t >> 6, lane = t & 63;
    const int r = blockIdx.x * 4 + wave;
    if (r >= Bn) return;
    const int lab = labels[r];
    const int n = classCount[lab];
    const int base = lab * MEMSTRIDE;
    const float mx = fdec(negmax[r]);
    const unsigned short* prow = pairsim + (size_t)r * Bn;

    float ps = 0.f, pc = 0.f;
    for (int j = lane; j < n; j += 64) {
        const int m = members[base + j];
        if (m != r) {
            const float s = bf2f(prow[m]);
            if ((s - MARGIN_C) < mx) {
                ps += __expf(-2.f * s);
                pc += 1.f;
            }
        }
    }
#pragma unroll
    for (int o = 32; o; o >>= 1) {
        ps += __shfl_down(ps, o, 64);
        pc += __shfl_down(pc, o, 64);
    }
    if (lane == 0) {
        possum[r] = ps;
        nposf[r] = pc;
    }
}

// ---------- finalize: class histogram + per-row loss + mean (single block) ---
__global__ __launch_bounds__(1024) void finalize(const float* __restrict__ negsum,
                                                 const float* __restrict__ possum,
                                                 const float* __restrict__ nposf,
                                                 const int* __restrict__ labels,
                                                 float* __restrict__ out, int Bn) {
    __shared__ int hist[NCLS];
    __shared__ float red[16];
    const int t = threadIdx.x;
    const int wave = t >> 6, lane = t & 63;
    if (t < NCLS) hist[t] = 0;
    __syncthreads();
    for (int i = t; i < Bn; i += 1024) atomicAdd(&hist[labels[i]], 1);
    __syncthreads();
    float acc = 0.f;
    for (int i = t; i < Bn; i += 1024) {
        const int nneg = Bn - hist[labels[i]];
        const float np = nposf[i];
        if (nneg >= 1 && np >= 0.5f) {
            float pl = 0.5f * logf((possum[i] + expf(-2.f * 0.501f)) / (np + 1.f));
            float nl = (1.f / 40.f) * logf((negsum[i] + expf(40.f * 0.531f)) / ((float)nneg + 1.f));
            acc += logf(5.33f + expf(pl + nl));
        }
    }
#pragma unroll
    for (int o = 32; o; o >>= 1) acc += __shfl_down(acc, o, 64);
    if (lane == 0) red[wave] = acc;
    __syncthreads();
    if (t == 0) {
        float s = 0.f;
        for (int w = 0; w < 16; w++) s += red[w];
        out[0] = s / (float)Bn;
    }
}

extern "C" void kernel_launch(void* const* d_in, const int* in_sizes, int n_in,
                              void* d_out, int out_size, void* d_ws, size_t ws_size,
                              hipStream_t stream) {
    const float* feats = (const float*)d_in[0];
    const int* labels  = (const int*)d_in[1];
    float* out = (float*)d_out;

    const int Bn = in_sizes[1];           // 4096
    const int Dn = in_sizes[0] / Bn;      // 1024

    unsigned short* fb = (unsigned short*)d_ws;                 // bf16 feats [Bn][Dn]
    float* stats    = (float*)(fb + (size_t)Bn * Dn);
    float* negsum   = stats;                                    // [Bn]
    unsigned* negmax = (unsigned*)(stats + Bn);                 // [Bn] keyed
    float* possum   = stats + 2 * Bn;                           // [Bn] (written, no init)
    float* nposf    = stats + 3 * Bn;                           // [Bn] (written, no init)
    int* classCount = (int*)(stats + 4 * Bn);                   // [NCLS]
    int* members    = classCount + NCLS;                        // [NCLS][MEMSTRIDE]
    unsigned short* pairsim = (unsigned short*)(members + NCLS * MEMSTRIDE); // [Bn][Bn] bf16

    const int n4   = (Bn * Dn) / 4;
    const int nz4  = (2 * Bn) / 4;        // zero negsum+negmax only
    const int ncvt = (n4 + 255) / 256;
    cvt_build<<<ncvt + NCLS, 256, 0, stream>>>(feats, fb, stats, labels,
                                               members, classCount, n4, nz4, ncvt, Bn);

    const int nt = Bn / 128;
    const int ntri = nt * (nt + 1) / 2;   // 528
    gemm_fused<<<ntri, 256, 0, stream>>>(fb, labels, negsum, negmax, pairsim, Bn, Dn);

    pos_apply<<<(Bn + 3) / 4, 256, 0, stream>>>(pairsim, labels, members, classCount,
                                                negmax, possum, nposf, Bn);

    finalize<<<1, 1024, 0, stream>>>(negsum, possum, nposf, labels, out, Bn);
}